// Round 10
// baseline (114.987 us; speedup 1.0000x reference)
//
#include <hip/hip_runtime.h>

// Round 10: MFMA chain with stacked-K operand layout (k=4g+j low, 16+4g+j high).
// Key property: D rows 4g+r == next-MFMA B k-slots 4g+j, and st occupies the
// low K-block => recurrent feedback is lane-local, ZERO shuffles in the loop.
// 16 elements/wave, 4096 waves (4/SIMD, grid-limited). Only builtin used:
// mfma_f32_16x16x32_f16 (host-pass-safe, on verified gfx950 list).

#define NB   65536
#define NS   64
#define OBSD 20
#define NH   10

typedef __fp16 f16x2 __attribute__((ext_vector_type(2)));
typedef __fp16 half8 __attribute__((ext_vector_type(8)));
typedef float  f32x4 __attribute__((ext_vector_type(4)));

#define MFMA32(a,b,c) __builtin_amdgcn_mfma_f32_16x16x32_f16((a),(b),(c),0,0,0)

__device__ __forceinline__ float ftanh(float x) {
    float e = __builtin_amdgcn_exp2f(x * 2.885390081777927f);  // 2*log2(e)
    float r = __builtin_amdgcn_rcpf(1.0f + e);
    return fmaf(-2.0f, r, 1.0f);
}
__device__ __forceinline__ f16x2 pk(float a, float b) {
    return __builtin_amdgcn_cvt_pkrtz(a, b);
}
__device__ __forceinline__ float f2f(f16x2 v) { return __builtin_bit_cast(float, v); }
__device__ __forceinline__ f16x2 bcf(float v) { return __builtin_bit_cast(f16x2, v); }

union U8 { f16x2 w[4]; half8 v; };

__global__ __launch_bounds__(256, 4)
void rd_fwd(const float* __restrict__ states, const float* __restrict__ actions,
            const float* __restrict__ W1, const float* __restrict__ b1,
            const float* __restrict__ W2, const float* __restrict__ b2,
            const float* __restrict__ W3, const float* __restrict__ b3,
            const float* __restrict__ Wg1, const float* __restrict__ bg1,
            const float* __restrict__ Wg2, const float* __restrict__ bg2,
            float* __restrict__ out)
{
    const int lane = threadIdx.x & 63;
    const int wave = (blockIdx.x * blockDim.x + threadIdx.x) >> 6;
    const int e    = lane & 15;      // element (B/D column)
    const int g    = lane >> 4;      // k/row group
    const int E    = wave * 16 + e;  // global element
    const int n    = e;              // A row (output neuron)
    const bool nv  = (n < NH);

    // ---- A1 = W1^T (16x32), stacked-K: j<4 -> k=4g+j ; j>=4 -> k=16+4g+(j-4)
    U8 A1;
#pragma unroll
    for (int v = 0; v < 4; ++v) {
        const int k0 = (v < 2) ? (4 * g + 2 * v) : (16 + 4 * g + 2 * (v - 2));
        const float x0 = nv ? W1[k0 * NH + n] : 0.0f;
        const float x1 = nv ? W1[(k0 + 1) * NH + n] : 0.0f;
        A1.w[v] = pk(x0, x1);
    }
    // ---- A2/A3/Ah: valid k<10 lives in the low K-block (k=4g+j<10) ----
    U8 A2, A3, Ah;
    const f16x2 z = pk(0.0f, 0.0f);
#pragma unroll
    for (int v = 0; v < 4; ++v) {
        if (v < 2) {
            const int k0 = 4 * g + 2 * v;
            const bool v0 = nv && (k0 < NH), v1 = nv && (k0 + 1 < NH);
            A2.w[v] = pk(v0 ? W2[k0 * NH + n] : 0.0f, v1 ? W2[(k0 + 1) * NH + n] : 0.0f);
            A3.w[v] = pk(v0 ? W3[k0 * NH + n] : 0.0f, v1 ? W3[(k0 + 1) * NH + n] : 0.0f);
            Ah.w[v] = pk(v0 ? Wg1[k0 * NH + n] : 0.0f, v1 ? Wg1[(k0 + 1) * NH + n] : 0.0f);
        } else {
            A2.w[v] = z; A3.w[v] = z; Ah.w[v] = z;
        }
    }
    // ---- bias broadcasts in C/D layout: row nr = 4g+r ----
    f32x4 C1b, C2b, b3v, Chb;
    float wg2b[4];
#pragma unroll
    for (int r = 0; r < 4; ++r) {
        const int nr = 4 * g + r;
        const bool ok = (nr < NH);
        C1b[r] = ok ? b1[nr] : 0.0f;
        C2b[r] = ok ? b2[nr] : 0.0f;
        b3v[r] = ok ? b3[nr] : 0.0f;
        Chb[r] = ok ? bg1[nr] : 0.0f;
        wg2b[r] = ok ? Wg2[nr] : 0.0f;
    }
    // act word (consumed by g==3 lanes in B1.w[3] = k 30,31)
    const float2 av = *(const float2*)(actions + 2 * E);
    const f16x2 actw = pk(av.x, av.y);

    // ---- per-lane obs byte offsets (wave covers each 80B row exactly) ----
    // B1 obs needs: g0: obs6..9 | g1: obs10..13 | g2: obs0,1 + obs14..17
    //               g3: obs2..5 + obs18,19
    const int o0 = (g == 0) ? 24 : (g == 1) ? 40 : (g == 2) ? 0  : 8;
    const int o1 = (g == 0) ? 32 : (g == 1) ? 48 : (g == 2) ? 56 : 16;
    const int o2 = (g == 0) ? 32 : (g == 1) ? 48 : (g == 2) ? 64 : 72;

    const char* rowb = (const char*)(states + (size_t)E * (NS * OBSD));
    float2 R0 = *(const float2*)(rowb + o0);
    float2 R1 = *(const float2*)(rowb + o1);
    float2 R2 = *(const float2*)(rowb + o2);

    f32x4 st = {0.0f, 0.0f, 0.0f, 0.0f};
    float u0f = f2f(z), u1f = f2f(z);   // pk(st[4g],st[4g+1]), pk(st[4g+2],st[4g+3])

#pragma unroll 1
    for (int s = 0; s < NS; ++s) {
        const f16x2 ow0 = pk(R0.x, R0.y);
        const f16x2 ow1 = pk(R1.x, R1.y);
        const f16x2 ow2 = pk(R2.x, R2.y);

        // issue next step's loads (covered by this step's compute)
        {
            const int base = ((s < NS - 1) ? (s + 1) : s) * 80;
            R0 = *(const float2*)(rowb + base + o0);
            R1 = *(const float2*)(rowb + base + o1);
            R2 = *(const float2*)(rowb + base + o2);
        }

        // ---- assemble B1: x = [st(0..9), obs(10..29), act(30,31)] ----
        const f16x2 u0 = bcf(u0f), u1 = bcf(u1f);
        U8 B1;
        B1.w[0] = (g == 3) ? ow0 : u0;
        B1.w[1] = (g <= 1) ? u1  : (g == 2 ? ow0 : ow1);
        B1.w[2] = (g <= 1) ? ow0 : (g == 2 ? ow1 : ow2);
        B1.w[3] = (g <= 1) ? ow1 : (g == 2 ? ow2 : actw);

        // ---- layer 1 ----
        const f32x4 D1 = MFMA32(A1.v, B1.v, C1b);
        const float t0 = ftanh(D1[0]), t1 = ftanh(D1[1]),
                    t2 = ftanh(D1[2]), t3 = ftanh(D1[3]);
        U8 B2; B2.w[0] = pk(t0, t1); B2.w[1] = pk(t2, t3); B2.w[2] = z; B2.w[3] = z;

        // ---- layer 2 ----
        const f32x4 D2 = MFMA32(A2.v, B2.v, C2b);
        const float q0 = ftanh(D2[0]), q1 = ftanh(D2[1]),
                    q2 = ftanh(D2[2]), q3 = ftanh(D2[3]);
        U8 B3; B3.w[0] = pk(q0, q1); B3.w[1] = pk(q2, q3); B3.w[2] = z; B3.w[3] = z;

        // ---- layer 3: st' = W3^T h2 + (st + b3) ----
        f32x4 C3;
        C3[0] = st[0] + b3v[0]; C3[1] = st[1] + b3v[1];
        C3[2] = st[2] + b3v[2]; C3[3] = st[3] + b3v[3];
        st = MFMA32(A3.v, B3.v, C3);

        // pack st for next step's B1 (lane-local: rows 4g+r == k-slots 4g+j)
        u0f = f2f(pk(st[0], st[1]));
        u1f = f2f(pk(st[2], st[3]));
    }

    // ---- head: out = Wg2 . tanh(Wg1^T st + bg1) + bg2 ----
    U8 Bh; Bh.w[0] = bcf(u0f); Bh.w[1] = bcf(u1f); Bh.w[2] = z; Bh.w[3] = z;
    const f32x4 Dh = MFMA32(Ah.v, Bh.v, Chb);
    float part = 0.0f;
#pragma unroll
    for (int r = 0; r < 4; ++r) part = fmaf(ftanh(Dh[r]), wg2b[r], part);
    part += __shfl_xor(part, 16);
    part += __shfl_xor(part, 32);
    if (lane < 16) out[wave * 16 + lane] = part + bg2[0];
}

extern "C" void kernel_launch(void* const* d_in, const int* in_sizes, int n_in,
                              void* d_out, int out_size, void* d_ws, size_t ws_size,
                              hipStream_t stream) {
    const float* states  = (const float*)d_in[0];
    const float* actions = (const float*)d_in[1];
    const float* W1  = (const float*)d_in[2];
    const float* b1  = (const float*)d_in[3];
    const float* W2  = (const float*)d_in[4];
    const float* b2  = (const float*)d_in[5];
    const float* W3  = (const float*)d_in[6];
    const float* b3  = (const float*)d_in[7];
    const float* Wg1 = (const float*)d_in[8];
    const float* bg1 = (const float*)d_in[9];
    const float* Wg2 = (const float*)d_in[10];
    const float* bg2 = (const float*)d_in[11];
    float* out = (float*)d_out;

    // 65536 elements / 16 per wave = 4096 waves = 1024 blocks of 256
    rd_fwd<<<1024, 256, 0, stream>>>(states, actions, W1, b1, W2, b2,
                                     W3, b3, Wg1, bg1, Wg2, bg2, out);
}

// Round 11
// 111.844 us; speedup vs baseline: 1.0281x; 1.0281x over previous
//
#include <hip/hip_runtime.h>

// Round 11 = Round 10 (verified MFMA chain, stacked-K, zero in-loop shuffles)
// + prefetch depth 3: loads for step s+3 issued at step s, 4-deep static
// circular buffer, unroll-4 so all indices constant-fold (no scratch).
// Theory: wall/step was one full memory round-trip (1.5KB/wave in flight);
// tripling in-flight bytes cuts the latency term ~3x toward the 165MB fetch floor.

#define NB   65536
#define NS   64
#define OBSD 20
#define NH   10

typedef __fp16 f16x2 __attribute__((ext_vector_type(2)));
typedef __fp16 half8 __attribute__((ext_vector_type(8)));
typedef float  f32x4 __attribute__((ext_vector_type(4)));

#define MFMA32(a,b,c) __builtin_amdgcn_mfma_f32_16x16x32_f16((a),(b),(c),0,0,0)

__device__ __forceinline__ float ftanh(float x) {
    float e = __builtin_amdgcn_exp2f(x * 2.885390081777927f);  // 2*log2(e)
    float r = __builtin_amdgcn_rcpf(1.0f + e);
    return fmaf(-2.0f, r, 1.0f);
}
__device__ __forceinline__ f16x2 pk(float a, float b) {
    return __builtin_amdgcn_cvt_pkrtz(a, b);
}
__device__ __forceinline__ float f2f(f16x2 v) { return __builtin_bit_cast(float, v); }
__device__ __forceinline__ f16x2 bcf(float v) { return __builtin_bit_cast(f16x2, v); }

union U8 { f16x2 w[4]; half8 v; };

__global__ __launch_bounds__(256, 4)
void rd_fwd(const float* __restrict__ states, const float* __restrict__ actions,
            const float* __restrict__ W1, const float* __restrict__ b1,
            const float* __restrict__ W2, const float* __restrict__ b2,
            const float* __restrict__ W3, const float* __restrict__ b3,
            const float* __restrict__ Wg1, const float* __restrict__ bg1,
            const float* __restrict__ Wg2, const float* __restrict__ bg2,
            float* __restrict__ out)
{
    const int lane = threadIdx.x & 63;
    const int wave = (blockIdx.x * blockDim.x + threadIdx.x) >> 6;
    const int e    = lane & 15;      // element (B/D column)
    const int g    = lane >> 4;      // k/row group
    const int E    = wave * 16 + e;  // global element
    const int n    = e;              // A row (output neuron)
    const bool nv  = (n < NH);

    // ---- A1 = W1^T (16x32), stacked-K: j<4 -> k=4g+j ; j>=4 -> k=16+4g+(j-4)
    U8 A1;
#pragma unroll
    for (int v = 0; v < 4; ++v) {
        const int k0 = (v < 2) ? (4 * g + 2 * v) : (16 + 4 * g + 2 * (v - 2));
        const float x0 = nv ? W1[k0 * NH + n] : 0.0f;
        const float x1 = nv ? W1[(k0 + 1) * NH + n] : 0.0f;
        A1.w[v] = pk(x0, x1);
    }
    // ---- A2/A3/Ah: valid k<10 lives in the low K-block (k=4g+j<10) ----
    U8 A2, A3, Ah;
    const f16x2 z = pk(0.0f, 0.0f);
#pragma unroll
    for (int v = 0; v < 4; ++v) {
        if (v < 2) {
            const int k0 = 4 * g + 2 * v;
            const bool v0 = nv && (k0 < NH), v1 = nv && (k0 + 1 < NH);
            A2.w[v] = pk(v0 ? W2[k0 * NH + n] : 0.0f, v1 ? W2[(k0 + 1) * NH + n] : 0.0f);
            A3.w[v] = pk(v0 ? W3[k0 * NH + n] : 0.0f, v1 ? W3[(k0 + 1) * NH + n] : 0.0f);
            Ah.w[v] = pk(v0 ? Wg1[k0 * NH + n] : 0.0f, v1 ? Wg1[(k0 + 1) * NH + n] : 0.0f);
        } else {
            A2.w[v] = z; A3.w[v] = z; Ah.w[v] = z;
        }
    }
    // ---- bias broadcasts in C/D layout: row nr = 4g+r ----
    f32x4 C1b, C2b, b3v, Chb;
    float wg2b[4];
#pragma unroll
    for (int r = 0; r < 4; ++r) {
        const int nr = 4 * g + r;
        const bool ok = (nr < NH);
        C1b[r] = ok ? b1[nr] : 0.0f;
        C2b[r] = ok ? b2[nr] : 0.0f;
        b3v[r] = ok ? b3[nr] : 0.0f;
        Chb[r] = ok ? bg1[nr] : 0.0f;
        wg2b[r] = ok ? Wg2[nr] : 0.0f;
    }
    // act word (consumed by g==3 lanes in B1.w[3] = k 30,31)
    const float2 av = *(const float2*)(actions + 2 * E);
    const f16x2 actw = pk(av.x, av.y);

    // ---- per-lane obs byte offsets (wave covers each 80B row exactly) ----
    const int o0 = (g == 0) ? 24 : (g == 1) ? 40 : (g == 2) ? 0  : 8;
    const int o1 = (g == 0) ? 32 : (g == 1) ? 48 : (g == 2) ? 56 : 16;
    const int o2 = (g == 0) ? 32 : (g == 1) ? 48 : (g == 2) ? 64 : 72;

    const char* rowb = (const char*)(states + (size_t)E * (NS * OBSD));

    // ---- 4-deep prefetch buffers (static indices after unroll-4) ----
    float2 F[4][3];
#pragma unroll
    for (int d = 0; d < 3; ++d) {
        F[d][0] = *(const float2*)(rowb + d * 80 + o0);
        F[d][1] = *(const float2*)(rowb + d * 80 + o1);
        F[d][2] = *(const float2*)(rowb + d * 80 + o2);
    }

    f32x4 st = {0.0f, 0.0f, 0.0f, 0.0f};
    float u0f = f2f(z), u1f = f2f(z);   // pk(st[4g],st[4g+1]), pk(st[4g+2],st[4g+3])

#pragma unroll 4
    for (int s = 0; s < NS; ++s) {
        const int cur = s & 3;
        const f16x2 ow0 = pk(F[cur][0].x, F[cur][0].y);
        const f16x2 ow1 = pk(F[cur][1].x, F[cur][1].y);
        const f16x2 ow2 = pk(F[cur][2].x, F[cur][2].y);

        // issue loads for step s+3 into the slot just freed
        {
            const int sp = (s + 3 <= NS - 1) ? (s + 3) : (NS - 1);
            const int nb = (s + 3) & 3;
            F[nb][0] = *(const float2*)(rowb + sp * 80 + o0);
            F[nb][1] = *(const float2*)(rowb + sp * 80 + o1);
            F[nb][2] = *(const float2*)(rowb + sp * 80 + o2);
        }

        // ---- assemble B1: x = [st(0..9), obs(10..29), act(30,31)] ----
        const f16x2 u0 = bcf(u0f), u1 = bcf(u1f);
        U8 B1;
        B1.w[0] = (g == 3) ? ow0 : u0;
        B1.w[1] = (g <= 1) ? u1  : (g == 2 ? ow0 : ow1);
        B1.w[2] = (g <= 1) ? ow0 : (g == 2 ? ow1 : ow2);
        B1.w[3] = (g <= 1) ? ow1 : (g == 2 ? ow2 : actw);

        // ---- layer 1 ----
        const f32x4 D1 = MFMA32(A1.v, B1.v, C1b);
        const float t0 = ftanh(D1[0]), t1 = ftanh(D1[1]),
                    t2 = ftanh(D1[2]), t3 = ftanh(D1[3]);
        U8 B2; B2.w[0] = pk(t0, t1); B2.w[1] = pk(t2, t3); B2.w[2] = z; B2.w[3] = z;

        // ---- layer 2 ----
        const f32x4 D2 = MFMA32(A2.v, B2.v, C2b);
        const float q0 = ftanh(D2[0]), q1 = ftanh(D2[1]),
                    q2 = ftanh(D2[2]), q3 = ftanh(D2[3]);
        U8 B3; B3.w[0] = pk(q0, q1); B3.w[1] = pk(q2, q3); B3.w[2] = z; B3.w[3] = z;

        // ---- layer 3: st' = W3^T h2 + (st + b3) ----
        f32x4 C3;
        C3[0] = st[0] + b3v[0]; C3[1] = st[1] + b3v[1];
        C3[2] = st[2] + b3v[2]; C3[3] = st[3] + b3v[3];
        st = MFMA32(A3.v, B3.v, C3);

        // pack st for next step's B1 (lane-local: rows 4g+r == k-slots 4g+j)
        u0f = f2f(pk(st[0], st[1]));
        u1f = f2f(pk(st[2], st[3]));
    }

    // ---- head: out = Wg2 . tanh(Wg1^T st + bg1) + bg2 ----
    U8 Bh; Bh.w[0] = bcf(u0f); Bh.w[1] = bcf(u1f); Bh.w[2] = z; Bh.w[3] = z;
    const f32x4 Dh = MFMA32(Ah.v, Bh.v, Chb);
    float part = 0.0f;
#pragma unroll
    for (int r = 0; r < 4; ++r) part = fmaf(ftanh(Dh[r]), wg2b[r], part);
    part += __shfl_xor(part, 16);
    part += __shfl_xor(part, 32);
    if (lane < 16) out[wave * 16 + lane] = part + bg2[0];
}

extern "C" void kernel_launch(void* const* d_in, const int* in_sizes, int n_in,
                              void* d_out, int out_size, void* d_ws, size_t ws_size,
                              hipStream_t stream) {
    const float* states  = (const float*)d_in[0];
    const float* actions = (const float*)d_in[1];
    const float* W1  = (const float*)d_in[2];
    const float* b1  = (const float*)d_in[3];
    const float* W2  = (const float*)d_in[4];
    const float* b2  = (const float*)d_in[5];
    const float* W3  = (const float*)d_in[6];
    const float* b3  = (const float*)d_in[7];
    const float* Wg1 = (const float*)d_in[8];
    const float* bg1 = (const float*)d_in[9];
    const float* Wg2 = (const float*)d_in[10];
    const float* bg2 = (const float*)d_in[11];
    float* out = (float*)d_out;

    // 65536 elements / 16 per wave = 4096 waves = 1024 blocks of 256
    rd_fwd<<<1024, 256, 0, stream>>>(states, actions, W1, b1, W2, b2,
                                     W3, b3, Wg1, bg1, Wg2, bg2, out);
}

// Round 12
// 72.086 us; speedup vs baseline: 1.5951x; 1.5515x over previous
//
#include <hip/hip_runtime.h>

// Round 12 = R10 MFMA chain + DRAM-density fix.
// Theory: all prior designs touch each element's row 80 B per step ->
// DRAM page-activation-limited ~3 TB/s. Stage 8 steps (640 B contiguous
// per element) per tile through regs -> f16 -> LDS; compute reads LDS.
// Staging: 4 lanes x 16 B = coalesced 64-B segments, 10 dwordx4/lane/tile,
// issued one tile ahead (covered by ~2k cyc of compute).

#define NB      65536
#define NS      64
#define NH      10
#define TSTEPS  8
#define NTILES  8
#define LSTRIDE 328   // LDS bytes per element: 8 steps * 40 B (f16) + 8 pad

typedef __fp16 f16x2 __attribute__((ext_vector_type(2)));
typedef __fp16 half8 __attribute__((ext_vector_type(8)));
typedef float  f32x4 __attribute__((ext_vector_type(4)));

#define MFMA32(a,b,c) __builtin_amdgcn_mfma_f32_16x16x32_f16((a),(b),(c),0,0,0)

__device__ __forceinline__ float ftanh(float x) {
    float e = __builtin_amdgcn_exp2f(x * 2.885390081777927f);  // 2*log2(e)
    float r = __builtin_amdgcn_rcpf(1.0f + e);
    return fmaf(-2.0f, r, 1.0f);
}
__device__ __forceinline__ f16x2 pk(float a, float b) {
    return __builtin_amdgcn_cvt_pkrtz(a, b);
}
__device__ __forceinline__ float f2f(f16x2 v) { return __builtin_bit_cast(float, v); }
__device__ __forceinline__ f16x2 bcf(float v) { return __builtin_bit_cast(f16x2, v); }

union U8 { f16x2 w[4]; half8 v; };

__global__ __launch_bounds__(256, 4)
void rd_fwd(const float* __restrict__ states, const float* __restrict__ actions,
            const float* __restrict__ W1, const float* __restrict__ b1,
            const float* __restrict__ W2, const float* __restrict__ b2,
            const float* __restrict__ W3, const float* __restrict__ b3,
            const float* __restrict__ Wg1, const float* __restrict__ bg1,
            const float* __restrict__ Wg2, const float* __restrict__ bg2,
            float* __restrict__ out)
{
    __shared__ unsigned char lds[64 * LSTRIDE];   // 20,992 B

    const int tid  = threadIdx.x;
    const int lane = tid & 63;
    const int w    = tid >> 6;                 // wave in block
    const int wg   = blockIdx.x * 4 + w;       // global wave id
    const int e    = lane & 15;                // element (B/D column)
    const int g    = lane >> 4;                // k/row group
    const int E    = wg * 16 + e;              // global element
    const int n    = e;                        // A row (neuron)
    const bool nv  = (n < NH);
    const f16x2 z  = pk(0.0f, 0.0f);

    // ---- A1 = W1^T (16x32), stacked-K: j<4 -> k=4g+j ; j>=4 -> 16+4g+(j-4)
    U8 A1;
#pragma unroll
    for (int v = 0; v < 4; ++v) {
        const int k0 = (v < 2) ? (4 * g + 2 * v) : (16 + 4 * g + 2 * (v - 2));
        A1.w[v] = pk(nv ? W1[k0 * NH + n] : 0.0f,
                     nv ? W1[(k0 + 1) * NH + n] : 0.0f);
    }
    // ---- A2/A3: valid k<10 in low K-block ----
    U8 A2, A3;
#pragma unroll
    for (int v = 0; v < 4; ++v) {
        if (v < 2) {
            const int k0 = 4 * g + 2 * v;
            const bool v0 = nv && (k0 < NH), v1 = nv && (k0 + 1 < NH);
            A2.w[v] = pk(v0 ? W2[k0 * NH + n] : 0.0f, v1 ? W2[(k0 + 1) * NH + n] : 0.0f);
            A3.w[v] = pk(v0 ? W3[k0 * NH + n] : 0.0f, v1 ? W3[(k0 + 1) * NH + n] : 0.0f);
        } else { A2.w[v] = z; A3.w[v] = z; }
    }
    // ---- loop bias broadcasts (C/D row = 4g+r) ----
    f32x4 C1b, C2b, b3v;
#pragma unroll
    for (int r = 0; r < 4; ++r) {
        const int nr = 4 * g + r;
        const bool ok = (nr < NH);
        C1b[r] = ok ? b1[nr] : 0.0f;
        C2b[r] = ok ? b2[nr] : 0.0f;
        b3v[r] = ok ? b3[nr] : 0.0f;
    }
    const float2 av = *(const float2*)(actions + 2 * E);
    const f16x2 actw = pk(av.x, av.y);

    // ---- staging mapping: 4 lanes per element, coalesced 64-B segments ----
    const int se = lane >> 2, sq = lane & 3;
    const char* gsrc = (const char*)states + (size_t)(wg * 16 + se) * 5120 + sq * 16;
    unsigned char* lw = &lds[(w * 16 + se) * LSTRIDE + sq * 8];

    // ---- LDS read bases (f16 byte offsets = R10 f32 offsets / 2) ----
    const unsigned char* lr = &lds[(w * 16 + e) * LSTRIDE];
    const int r0 = (g == 0) ? 12 : (g == 1) ? 20 : (g == 2) ? 0  : 4;
    const int r1 = (g == 0) ? 16 : (g == 1) ? 24 : (g == 2) ? 28 : 8;
    const int r2 = (g == 0) ? 16 : (g == 1) ? 24 : (g == 2) ? 32 : 36;

    // ---- prologue: issue tile 0 loads ----
    float4 F[10];
#pragma unroll
    for (int i = 0; i < 10; ++i) F[i] = *(const float4*)(gsrc + i * 64);

    f32x4 st = {0.0f, 0.0f, 0.0f, 0.0f};
    float u0f = f2f(z), u1f = f2f(z);

#pragma unroll 1
    for (int t = 0; t < NTILES; ++t) {
        __syncthreads();   // all waves done reading previous tile
        // convert staged f32 -> f16 pairs, write to LDS
#pragma unroll
        for (int i = 0; i < 10; ++i) {
            const float4 f = F[i];
            uint2 pw;
            pw.x = __builtin_bit_cast(unsigned int, pk(f.x, f.y));
            pw.y = __builtin_bit_cast(unsigned int, pk(f.z, f.w));
            *(uint2*)(lw + i * 32) = pw;
        }
        // issue next tile's loads (land during this tile's compute)
        if (t < NTILES - 1) {
#pragma unroll
            for (int i = 0; i < 10; ++i)
                F[i] = *(const float4*)(gsrc + (t + 1) * 640 + i * 64);
        }
        __syncthreads();   // tile t visible

#pragma unroll
        for (int s = 0; s < TSTEPS; ++s) {
            const int sb = s * 40;
            const f16x2 ow0 = bcf(*(const float*)(lr + sb + r0));
            const f16x2 ow1 = bcf(*(const float*)(lr + sb + r1));
            const f16x2 ow2 = bcf(*(const float*)(lr + sb + r2));

            // ---- B1: x = [st(0..9), obs(10..29), act(30,31)] ----
            const f16x2 u0 = bcf(u0f), u1 = bcf(u1f);
            U8 B1;
            B1.w[0] = (g == 3) ? ow0 : u0;
            B1.w[1] = (g <= 1) ? u1  : (g == 2 ? ow0 : ow1);
            B1.w[2] = (g <= 1) ? ow0 : (g == 2 ? ow1 : ow2);
            B1.w[3] = (g <= 1) ? ow1 : (g == 2 ? ow2 : actw);

            // ---- layer 1 ----
            const f32x4 D1 = MFMA32(A1.v, B1.v, C1b);
            const float t0 = ftanh(D1[0]), t1 = ftanh(D1[1]),
                        t2 = ftanh(D1[2]), t3 = ftanh(D1[3]);
            U8 B2; B2.w[0] = pk(t0, t1); B2.w[1] = pk(t2, t3);
            B2.w[2] = z; B2.w[3] = z;

            // ---- layer 2 ----
            const f32x4 D2 = MFMA32(A2.v, B2.v, C2b);
            const float q0 = ftanh(D2[0]), q1 = ftanh(D2[1]),
                        q2 = ftanh(D2[2]), q3 = ftanh(D2[3]);
            U8 B3; B3.w[0] = pk(q0, q1); B3.w[1] = pk(q2, q3);
            B3.w[2] = z; B3.w[3] = z;

            // ---- layer 3: st' = W3^T h2 + (st + b3) ----
            f32x4 C3;
            C3[0] = st[0] + b3v[0]; C3[1] = st[1] + b3v[1];
            C3[2] = st[2] + b3v[2]; C3[3] = st[3] + b3v[3];
            st = MFMA32(A3.v, B3.v, C3);

            u0f = f2f(pk(st[0], st[1]));
            u1f = f2f(pk(st[2], st[3]));
        }
    }

    // ---- head (weights loaded only now: lower loop register pressure) ----
    U8 Ah;
#pragma unroll
    for (int v = 0; v < 4; ++v) {
        if (v < 2) {
            const int k0 = 4 * g + 2 * v;
            const bool v0 = nv && (k0 < NH), v1 = nv && (k0 + 1 < NH);
            Ah.w[v] = pk(v0 ? Wg1[k0 * NH + n] : 0.0f, v1 ? Wg1[(k0 + 1) * NH + n] : 0.0f);
        } else Ah.w[v] = z;
    }
    f32x4 Chb;
    float wg2b[4];
#pragma unroll
    for (int r = 0; r < 4; ++r) {
        const int nr = 4 * g + r;
        Chb[r]  = (nr < NH) ? bg1[nr] : 0.0f;
        wg2b[r] = (nr < NH) ? Wg2[nr] : 0.0f;
    }
    U8 Bh; Bh.w[0] = bcf(u0f); Bh.w[1] = bcf(u1f); Bh.w[2] = z; Bh.w[3] = z;
    const f32x4 Dh = MFMA32(Ah.v, Bh.v, Chb);
    float part = 0.0f;
#pragma unroll
    for (int r = 0; r < 4; ++r) part = fmaf(ftanh(Dh[r]), wg2b[r], part);
    part += __shfl_xor(part, 16);
    part += __shfl_xor(part, 32);
    if (lane < 16) out[wg * 16 + lane] = part + bg2[0];
}

extern "C" void kernel_launch(void* const* d_in, const int* in_sizes, int n_in,
                              void* d_out, int out_size, void* d_ws, size_t ws_size,
                              hipStream_t stream) {
    const float* states  = (const float*)d_in[0];
    const float* actions = (const float*)d_in[1];
    const float* W1  = (const float*)d_in[2];
    const float* b1  = (const float*)d_in[3];
    const float* W2  = (const float*)d_in[4];
    const float* b2  = (const float*)d_in[5];
    const float* W3  = (const float*)d_in[6];
    const float* b3  = (const float*)d_in[7];
    const float* Wg1 = (const float*)d_in[8];
    const float* bg1 = (const float*)d_in[9];
    const float* Wg2 = (const float*)d_in[10];
    const float* bg2 = (const float*)d_in[11];
    float* out = (float*)d_out;

    // 65536 elements / 16 per wave / 4 waves per block = 1024 blocks
    rd_fwd<<<1024, 256, 0, stream>>>(states, actions, W1, b1, W2, b2,
                                     W3, b3, Wg1, bg1, Wg2, bg2, out);
}